// Round 9
// baseline (675.758 us; speedup 1.0000x reference)
//
#include <hip/hip_runtime.h>

#define NN 100000
#define NE 1600000
#define NPB 256                    // nodes per bucket
#define NB 391                     // ceil(NN/NPB)
#define CAP 4864                   // bucket capacity (mean 4092, sd 64)
#define NBLK_A 512
#define CHUNK_A (NE / NBLK_A)      // 3125
#define FM_N (NN * 16)             // 8 chunks * NN * 2 halves = 1.6M prep threads

typedef __attribute__((ext_vector_type(8))) short bf16x8;
typedef __attribute__((ext_vector_type(4))) float f32x4;

// ---------------- bf16 helpers (stored as ushort/uint, math in fp32) ----------------

__device__ __forceinline__ unsigned short f2bf(float f) {
    unsigned int u = __float_as_uint(f);
    unsigned int r = u + 0x7fffu + ((u >> 16) & 1u);  // RNE
    return (unsigned short)(r >> 16);
}
__device__ __forceinline__ float bflo(unsigned int u) { return __uint_as_float(u << 16); }
__device__ __forceinline__ float bfhi(unsigned int u) { return __uint_as_float(u & 0xffff0000u); }
__device__ __forceinline__ unsigned int packbf(float lo, float hi) {
    return ((unsigned int)f2bf(hi) << 16) | (unsigned int)f2bf(lo);
}
__device__ __forceinline__ bf16x8 as_bf8(uint4 u) {
    union { uint4 u; bf16x8 h; } c;
    c.u = u;
    return c.h;
}

// ---------------- CSR build phase A: scatter edges into 391 dst-buckets ----------------
// Packed entry: (d & 255) << 24 | src   (src < 2^17).

__global__ __launch_bounds__(256) void bucket_scatter_kernel(
    const int* __restrict__ src, const int* __restrict__ dst,
    int* __restrict__ gcur, unsigned* __restrict__ buckets) {
    __shared__ int hist[NB];
    __shared__ int base[NB];
    int t = threadIdx.x;
    for (int b = t; b < NB; b += 256) hist[b] = 0;
    __syncthreads();
    int e0 = blockIdx.x * CHUNK_A;
    for (int e = e0 + t; e < e0 + CHUNK_A; e += 256)
        atomicAdd(&hist[dst[e] >> 8], 1);
    __syncthreads();
    for (int b = t; b < NB; b += 256) {
        base[b] = atomicAdd(&gcur[b], hist[b]);
        hist[b] = 0;
    }
    __syncthreads();
    for (int e = e0 + t; e < e0 + CHUNK_A; e += 256) {
        int d = dst[e];
        int bkt = d >> 8;
        int slot = base[bkt] + atomicAdd(&hist[bkt], 1);
        if (slot < CAP)
            buckets[(size_t)bkt * CAP + slot] =
                ((unsigned)(d & 255) << 24) | (unsigned)src[e];
    }
}

// ---------------- CSR build: parallel scan of bucket totals (1 block) ----------------

__global__ __launch_bounds__(512) void bucket_scan_kernel(
    const int* __restrict__ gcur, int* __restrict__ bstart, int* __restrict__ row_ptr) {
    __shared__ int s[512];
    int t = threadIdx.x;
    int v = (t < NB) ? gcur[t] : 0;
    s[t] = v;
    __syncthreads();
    for (int off = 1; off < 512; off <<= 1) {
        int a = (t >= off) ? s[t - off] : 0;
        __syncthreads();
        s[t] += a;
        __syncthreads();
    }
    if (t < NB) bstart[t] = s[t] - v;
    if (t == NB - 1) {
        bstart[NB] = s[t];
        row_ptr[NN] = s[t];
    }
}

// ---------------- CSR build phase B: per-bucket finalize (all LDS atomics) ----------------

__global__ __launch_bounds__(256) void csr_finalize_kernel(
    const unsigned* __restrict__ buckets, const int* __restrict__ gcur,
    const int* __restrict__ bstart, int* __restrict__ row_ptr, int* __restrict__ adj) {
    __shared__ int hist[NPB];
    __shared__ int scn[NPB];
    int b = blockIdx.x;
    int t = threadIdx.x;
    int n = gcur[b];
    if (n > CAP) n = CAP;
    int base = bstart[b];
    const unsigned* bk = buckets + (size_t)b * CAP;

    hist[t] = 0;
    __syncthreads();
    for (int i = t; i < n; i += 256) atomicAdd(&hist[bk[i] >> 24], 1);
    __syncthreads();

    int v = hist[t];
    scn[t] = v;
    __syncthreads();
    for (int off = 1; off < 256; off <<= 1) {
        int add = (t >= off) ? scn[t - off] : 0;
        __syncthreads();
        scn[t] += add;
        __syncthreads();
    }
    int excl = scn[t] - v;
    int node = b * NPB + t;
    if (node < NN) row_ptr[node] = base + excl;

    hist[t] = excl;  // reuse as cursor
    __syncthreads();
    for (int i = t; i < n; i += 256) {
        unsigned pr = bk[i];
        int pos = atomicAdd(&hist[pr >> 24], 1);
        adj[base + pos] = (int)(pr & 0xFFFFFFu);
    }
}

// ---------------- prep: x -> feature-major bf16 [8][NN][16] AND weight frags ----------------
// frag[(kt*(H/16)+nt)*64 + lane], elem i = W[kt*32 + (lane>>4)*8 + i][nt*16 + (lane&15)]

__device__ __forceinline__ void wfrag_one(const float* __restrict__ W, int H, int idx,
                                          uint4* __restrict__ out) {
    int lane = idx & 63;
    int tile = idx >> 6;
    int ntiles = H >> 4;
    int nt = tile % ntiles;
    int kt = tile / ntiles;
    int kbase = kt * 32 + (lane >> 4) * 8;
    int col = nt * 16 + (lane & 15);
    uint4 r;
    r.x = packbf(W[(size_t)(kbase + 0) * H + col], W[(size_t)(kbase + 1) * H + col]);
    r.y = packbf(W[(size_t)(kbase + 2) * H + col], W[(size_t)(kbase + 3) * H + col]);
    r.z = packbf(W[(size_t)(kbase + 4) * H + col], W[(size_t)(kbase + 5) * H + col]);
    r.w = packbf(W[(size_t)(kbase + 6) * H + col], W[(size_t)(kbase + 7) * H + col]);
    out[idx] = r;
}

__global__ __launch_bounds__(256) void prep_kernel(
    const float* __restrict__ x, uint4* __restrict__ xfm4,
    const float* __restrict__ W1l, const float* __restrict__ W1r,
    const float* __restrict__ W2l, const float* __restrict__ W2r,
    const float* __restrict__ W3l, const float* __restrict__ W3r,
    uint4* __restrict__ wf1, uint4* __restrict__ wf2,
    uint4* __restrict__ wf3l, uint4* __restrict__ wf3r) {
    int idx = blockIdx.x * blockDim.x + threadIdx.x;
    if (idx < FM_N) {
        int c = idx / (NN * 2);
        int rem = idx - c * (NN * 2);
        int n = rem >> 1;
        int h = rem & 1;
        const float* p = x + (size_t)n * 128 + c * 16 + h * 8;
        float4 a = *(const float4*)p;
        float4 b = *(const float4*)(p + 4);
        uint4 r;
        r.x = packbf(a.x, a.y);
        r.y = packbf(a.z, a.w);
        r.z = packbf(b.x, b.y);
        r.w = packbf(b.z, b.w);
        xfm4[((size_t)c * NN + n) * 2 + h] = r;
    } else {
        int k = idx - FM_N;
        if (k < 2048)       wfrag_one(W1l, 128, k, wf1);
        else if (k < 4096)  wfrag_one(W1r, 128, k - 2048, wf1 + 2048);
        else if (k < 6144)  wfrag_one(W2l, 128, k - 4096, wf2);
        else if (k < 8192)  wfrag_one(W2r, 128, k - 6144, wf2 + 2048);
        else if (k < 9216)  wfrag_one(W3l, 64, k - 8192, wf3l);
        else if (k < 10240) wfrag_one(W3r, 64, k - 9216, wf3r);
    }
}

// ---------------- pull_mean 128-wide, feature-major, XCD-partitioned ----------------
// Grid = 6250 node-groups x 8 chunks; chunk = blockIdx&7 (pins chunk slice to one XCD L2).
// Block 256 thr = 4 waves x 4 nodes. Wave lanes: e = l&15 (edge), wd = l>>4 (8B word of 32B chunk).
// Writes row-major agg [NN][256B] for the GEMM.

__global__ __launch_bounds__(256) void pull128_fm_kernel(
    const uint2* __restrict__ xfm2, const int* __restrict__ row_ptr,
    const int* __restrict__ adj, uint2* __restrict__ agg2) {
    const int c = blockIdx.x & 7;
    const int ng = blockIdx.x >> 3;
    const int w = threadIdx.x >> 6;
    const int l = threadIdx.x & 63;
    const int e = l & 15;
    const int wd = l >> 4;
    const uint2* slice = xfm2 + (size_t)c * NN * 4;

#pragma unroll
    for (int k = 0; k < 4; ++k) {
        int node = ng * 16 + w * 4 + k;
        int beg = row_ptr[node], end = row_ptr[node + 1];
        float a0 = 0.f, a1 = 0.f, a2 = 0.f, a3 = 0.f;
        for (int p = beg; p < end; p += 16) {
            int ee = p + e;
            bool v = ee < end;
            int s = v ? adj[ee] : 0;
            uint2 u = slice[(size_t)s * 4 + wd];
            float m = v ? 1.f : 0.f;
            a0 = fmaf(m, bflo(u.x), a0);
            a1 = fmaf(m, bfhi(u.x), a1);
            a2 = fmaf(m, bflo(u.y), a2);
            a3 = fmaf(m, bfhi(u.y), a3);
        }
#pragma unroll
        for (int msk = 1; msk < 16; msk <<= 1) {
            a0 += __shfl_xor(a0, msk);
            a1 += __shfl_xor(a1, msk);
            a2 += __shfl_xor(a2, msk);
            a3 += __shfl_xor(a3, msk);
        }
        if (e == 0) {
            float inv = 1.0f / (float)(end > beg ? (end - beg) : 1);
            uint2 r;
            r.x = packbf(a0 * inv, a1 * inv);
            r.y = packbf(a2 * inv, a3 * inv);
            agg2[(size_t)node * 32 + c * 4 + wd] = r;
        }
    }
}

// ---------------- pull_mean 64-wide (z), feature-major [8][NN][8], fp32 out ----------------
// lane: e = l&15 (edge), wd = l>>4 (4B word of 16B chunk). Writes row-major agg3 [NN][64] fp32.

__global__ __launch_bounds__(256) void pull64_fm_kernel(
    const unsigned* __restrict__ zfm1, const int* __restrict__ row_ptr,
    const int* __restrict__ adj, float* __restrict__ agg3) {
    const int c = blockIdx.x & 7;
    const int ng = blockIdx.x >> 3;
    const int w = threadIdx.x >> 6;
    const int l = threadIdx.x & 63;
    const int e = l & 15;
    const int wd = l >> 4;
    const unsigned* slice = zfm1 + (size_t)c * NN * 4;

#pragma unroll
    for (int k = 0; k < 4; ++k) {
        int node = ng * 16 + w * 4 + k;
        int beg = row_ptr[node], end = row_ptr[node + 1];
        float a0 = 0.f, a1 = 0.f;
        for (int p = beg; p < end; p += 16) {
            int ee = p + e;
            bool v = ee < end;
            int s = v ? adj[ee] : 0;
            unsigned u = slice[(size_t)s * 4 + wd];
            float m = v ? 1.f : 0.f;
            a0 = fmaf(m, bflo(u), a0);
            a1 = fmaf(m, bfhi(u), a1);
        }
#pragma unroll
        for (int msk = 1; msk < 16; msk <<= 1) {
            a0 += __shfl_xor(a0, msk);
            a1 += __shfl_xor(a1, msk);
        }
        if (e == 0) {
            float inv = 1.0f / (float)(end > beg ? (end - beg) : 1);
            float2 r;
            r.x = a0 * inv;
            r.y = a1 * inv;
            *(float2*)(agg3 + (size_t)node * 64 + c * 8 + wd * 2) = r;
        }
    }
}

// ---------------- MFMA SAGE layer: h_fm = relu(agg@Wl + x_fm@Wr + b), feature-major out ----------------

__global__ __launch_bounds__(256) void sage_mfma_kernel(
    const uint4* __restrict__ agg4, const uint4* __restrict__ xfm4,
    const uint4* __restrict__ wfrag, const float* __restrict__ bias,
    unsigned short* __restrict__ outfm) {
    const int w = threadIdx.x >> 6;
    const int l = threadIdx.x & 63;
    const int r0 = blockIdx.x * 64 + w * 16;
    int arow = r0 + (l & 15);
    if (arow > NN - 1) arow = NN - 1;
    const int g = l >> 4;

    f32x4 acc[8];
#pragma unroll
    for (int nt = 0; nt < 8; ++nt) {
        f32x4 z = {0.f, 0.f, 0.f, 0.f};
        acc[nt] = z;
    }

#pragma unroll
    for (int kt = 0; kt < 4; ++kt) {  // agg half (row-major)
        bf16x8 av = as_bf8(agg4[(size_t)arow * 16 + kt * 4 + g]);
#pragma unroll
        for (int nt = 0; nt < 8; ++nt) {
            bf16x8 bv = as_bf8(wfrag[(kt * 8 + nt) * 64 + l]);
            acc[nt] = __builtin_amdgcn_mfma_f32_16x16x32_bf16(av, bv, acc[nt], 0, 0, 0);
        }
    }
#pragma unroll
    for (int kt = 4; kt < 8; ++kt) {  // xin half (feature-major)
        int c = 2 * (kt - 4) + (g >> 1);
        bf16x8 av = as_bf8(xfm4[((size_t)c * NN + arow) * 2 + (g & 1)]);
#pragma unroll
        for (int nt = 0; nt < 8; ++nt) {
            bf16x8 bv = as_bf8(wfrag[(kt * 8 + nt) * 64 + l]);
            acc[nt] = __builtin_amdgcn_mfma_f32_16x16x32_bf16(av, bv, acc[nt], 0, 0, 0);
        }
    }

    const int crow0 = r0 + ((l >> 4) << 2);
    const int ccol = l & 15;
#pragma unroll
    for (int nt = 0; nt < 8; ++nt) {  // chunk = nt (16 feats)
        float bb = bias[nt * 16 + ccol];
#pragma unroll
        for (int q = 0; q < 4; ++q) {
            int r = crow0 + q;
            if (r < NN) {
                float v = fmaxf(acc[nt][q] + bb, 0.f);
                outfm[((size_t)nt * NN + r) * 16 + ccol] = f2bf(v);
            }
        }
    }
}

// ---------------- MFMA matmul from feature-major h2 (K=128 -> H=64) ----------------
// MODE 0: z_fm out ([8][NN][8] bf16).  MODE 1: fp32 out = acc + addin + bias.

template <int MODE>
__global__ __launch_bounds__(256) void mm64_mfma_kernel(
    const uint4* __restrict__ hfm4, const uint4* __restrict__ wfrag,
    const float* __restrict__ addin, const float* __restrict__ bias,
    void* __restrict__ outp) {
    const int w = threadIdx.x >> 6;
    const int l = threadIdx.x & 63;
    const int r0 = blockIdx.x * 64 + w * 16;
    int arow = r0 + (l & 15);
    if (arow > NN - 1) arow = NN - 1;
    const int g = l >> 4;

    f32x4 acc[4];
#pragma unroll
    for (int nt = 0; nt < 4; ++nt) {
        f32x4 z = {0.f, 0.f, 0.f, 0.f};
        acc[nt] = z;
    }

#pragma unroll
    for (int kt = 0; kt < 4; ++kt) {
        int c = 2 * kt + (g >> 1);
        bf16x8 av = as_bf8(hfm4[((size_t)c * NN + arow) * 2 + (g & 1)]);
#pragma unroll
        for (int nt = 0; nt < 4; ++nt) {
            bf16x8 bv = as_bf8(wfrag[(kt * 4 + nt) * 64 + l]);
            acc[nt] = __builtin_amdgcn_mfma_f32_16x16x32_bf16(av, bv, acc[nt], 0, 0, 0);
        }
    }

    const int crow0 = r0 + ((l >> 4) << 2);
    const int ccol = l & 15;
#pragma unroll
    for (int nt = 0; nt < 4; ++nt) {
        int col = nt * 16 + ccol;
#pragma unroll
        for (int q = 0; q < 4; ++q) {
            int r = crow0 + q;
            if (r < NN) {
                if (MODE == 0) {
                    int zc = 2 * nt + (ccol >> 3);
                    ((unsigned short*)outp)[((size_t)zc * NN + r) * 8 + (ccol & 7)] =
                        f2bf(acc[nt][q]);
                } else {
                    float v = acc[nt][q] + addin[(size_t)r * 64 + col] + bias[col];
                    ((float*)outp)[(size_t)r * 64 + col] = v;
                }
            }
        }
    }
}

// ---------------- launcher ----------------

extern "C" void kernel_launch(void* const* d_in, const int* in_sizes, int n_in,
                              void* d_out, int out_size, void* d_ws, size_t ws_size,
                              hipStream_t stream) {
    (void)in_sizes; (void)n_in; (void)out_size; (void)ws_size;

    const float* x   = (const float*)d_in[0];
    const int* eidx  = (const int*)d_in[1];
    const int* src   = eidx;
    const int* dst   = eidx + NE;
    const float* W1l = (const float*)d_in[2];
    const float* W1r = (const float*)d_in[3];
    const float* b1  = (const float*)d_in[4];
    const float* W2l = (const float*)d_in[5];
    const float* W2r = (const float*)d_in[6];
    const float* b2  = (const float*)d_in[7];
    const float* W3l = (const float*)d_in[8];
    const float* W3r = (const float*)d_in[9];
    const float* b3  = (const float*)d_in[10];
    float* out = (float*)d_out;

    size_t off = 0;
    auto carve = [&](size_t bytes) -> void* {
        void* p = (char*)d_ws + off;
        off += (bytes + 255) & ~(size_t)255;
        return p;
    };
    int* gcur    = (int*)carve((size_t)NB * 4);
    int* bstart  = (int*)carve((size_t)(NB + 1) * 4);
    int* row_ptr = (int*)carve((size_t)(NN + 1) * 4);
    int* adj     = (int*)carve((size_t)NE * 4);
    unsigned* buckets = (unsigned*)carve((size_t)NB * CAP * 4);         // 7.6 MB
    unsigned int* x_fm  = (unsigned int*)carve((size_t)NN * 64 * 4);    // [8][NN][16] bf16
    unsigned int* agg   = (unsigned int*)carve((size_t)NN * 64 * 4);    // row-major [NN][128] bf16
    unsigned int* h1_fm = (unsigned int*)carve((size_t)NN * 64 * 4);
    unsigned int* h2_fm = (unsigned int*)carve((size_t)NN * 64 * 4);
    unsigned int* z_fm  = (unsigned int*)carve((size_t)NN * 32 * 4);    // [8][NN][8] bf16
    float* agg3         = (float*)carve((size_t)NN * 64 * 4);           // row-major [NN][64] fp32
    uint4* wf1  = (uint4*)carve((size_t)8 * 8 * 64 * 16);
    uint4* wf2  = (uint4*)carve((size_t)8 * 8 * 64 * 16);
    uint4* wf3l = (uint4*)carve((size_t)4 * 4 * 64 * 16);
    uint4* wf3r = (uint4*)carve((size_t)4 * 4 * 64 * 16);

    const int pull_grid = (NN / 16) * 8;                    // 6250 * 8 = 50000
    const int mgrid = (NN + 63) / 64;                       // 1563
    const int pgrid = (FM_N + 10240 + 255) / 256;           // 6291

    // --- CSR build: scatter -> scan -> per-bucket finalize ---
    hipMemsetAsync(gcur, 0, (size_t)NB * 4, stream);
    bucket_scatter_kernel<<<NBLK_A, 256, 0, stream>>>(src, dst, gcur, buckets);
    bucket_scan_kernel<<<1, 512, 0, stream>>>(gcur, bstart, row_ptr);
    csr_finalize_kernel<<<NB, 256, 0, stream>>>(buckets, gcur, bstart, row_ptr, adj);

    // --- prep: x -> feature-major bf16 + weight frags ---
    prep_kernel<<<pgrid, 256, 0, stream>>>(x, (uint4*)x_fm, W1l, W1r, W2l, W2r, W3l, W3r,
                                           wf1, wf2, wf3l, wf3r);

    // --- layer 1 ---
    pull128_fm_kernel<<<pull_grid, 256, 0, stream>>>((const uint2*)x_fm, row_ptr, adj,
                                                     (uint2*)agg);
    sage_mfma_kernel<<<mgrid, 256, 0, stream>>>((const uint4*)agg, (const uint4*)x_fm,
                                                wf1, b1, (unsigned short*)h1_fm);
    // --- layer 2 ---
    pull128_fm_kernel<<<pull_grid, 256, 0, stream>>>((const uint2*)h1_fm, row_ptr, adj,
                                                     (uint2*)agg);
    sage_mfma_kernel<<<mgrid, 256, 0, stream>>>((const uint4*)agg, (const uint4*)h1_fm,
                                                wf2, b2, (unsigned short*)h2_fm);
    // --- layer 3: z = h2 @ W3l (feature-major), pull, out = h2 @ W3r + agg3 + b3 ---
    mm64_mfma_kernel<0><<<mgrid, 256, 0, stream>>>((const uint4*)h2_fm, wf3l,
                                                   nullptr, nullptr, z_fm);
    pull64_fm_kernel<<<pull_grid, 256, 0, stream>>>((const unsigned*)z_fm, row_ptr, adj, agg3);
    mm64_mfma_kernel<1><<<mgrid, 256, 0, stream>>>((const uint4*)h2_fm, wf3r, agg3, b3, out);
}

// Round 11
// 300.600 us; speedup vs baseline: 2.2480x; 2.2480x over previous
//
#include <hip/hip_runtime.h>

#define NN 100000
#define NE 1600000
#define NPB 256                    // nodes per bucket
#define NB 391                     // ceil(NN/NPB)
#define CAP 4864                   // bucket capacity (mean 4092, sd 64)
#define NBLK_A 512
#define CHUNK_A (NE / NBLK_A)      // 3125
#define CVT_N (NN * 16)            // 1.6M cvt threads (8 floats each)

typedef __attribute__((ext_vector_type(8))) short bf16x8;
typedef __attribute__((ext_vector_type(4))) float f32x4;

// ---------------- bf16 helpers (stored as ushort/uint, math in fp32) ----------------

__device__ __forceinline__ unsigned short f2bf(float f) {
    unsigned int u = __float_as_uint(f);
    unsigned int r = u + 0x7fffu + ((u >> 16) & 1u);  // RNE
    return (unsigned short)(r >> 16);
}
__device__ __forceinline__ float bflo(unsigned int u) { return __uint_as_float(u << 16); }
__device__ __forceinline__ float bfhi(unsigned int u) { return __uint_as_float(u & 0xffff0000u); }
__device__ __forceinline__ unsigned int packbf(float lo, float hi) {
    return ((unsigned int)f2bf(hi) << 16) | (unsigned int)f2bf(lo);
}
__device__ __forceinline__ bf16x8 as_bf8(uint4 u) {
    union { uint4 u; bf16x8 h; } c;
    c.u = u;
    return c.h;
}

// ---------------- CSR build phase A: scatter edges into 391 dst-buckets ----------------
// Packed entry: (d & 255) << 24 | src   (src < 2^17).

__global__ __launch_bounds__(256) void bucket_scatter_kernel(
    const int* __restrict__ src, const int* __restrict__ dst,
    int* __restrict__ gcur, unsigned* __restrict__ buckets) {
    __shared__ int hist[NB];
    __shared__ int base[NB];
    int t = threadIdx.x;
    for (int b = t; b < NB; b += 256) hist[b] = 0;
    __syncthreads();
    int e0 = blockIdx.x * CHUNK_A;
    for (int e = e0 + t; e < e0 + CHUNK_A; e += 256)
        atomicAdd(&hist[dst[e] >> 8], 1);
    __syncthreads();
    for (int b = t; b < NB; b += 256) {
        base[b] = atomicAdd(&gcur[b], hist[b]);
        hist[b] = 0;
    }
    __syncthreads();
    for (int e = e0 + t; e < e0 + CHUNK_A; e += 256) {
        int d = dst[e];
        int bkt = d >> 8;
        int slot = base[bkt] + atomicAdd(&hist[bkt], 1);
        if (slot < CAP)
            buckets[(size_t)bkt * CAP + slot] =
                ((unsigned)(d & 255) << 24) | (unsigned)src[e];
    }
}

// ---------------- CSR build: parallel scan of bucket totals (1 block) ----------------

__global__ __launch_bounds__(512) void bucket_scan_kernel(
    const int* __restrict__ gcur, int* __restrict__ bstart, int* __restrict__ row_ptr) {
    __shared__ int s[512];
    int t = threadIdx.x;
    int v = (t < NB) ? gcur[t] : 0;
    s[t] = v;
    __syncthreads();
    for (int off = 1; off < 512; off <<= 1) {
        int a = (t >= off) ? s[t - off] : 0;
        __syncthreads();
        s[t] += a;
        __syncthreads();
    }
    if (t < NB) bstart[t] = s[t] - v;
    if (t == NB - 1) {
        bstart[NB] = s[t];
        row_ptr[NN] = s[t];
    }
}

// ---------------- CSR build phase B: per-bucket finalize (all LDS atomics) ----------------

__global__ __launch_bounds__(256) void csr_finalize_kernel(
    const unsigned* __restrict__ buckets, const int* __restrict__ gcur,
    const int* __restrict__ bstart, int* __restrict__ row_ptr, int* __restrict__ adj) {
    __shared__ int hist[NPB];
    __shared__ int scn[NPB];
    int b = blockIdx.x;
    int t = threadIdx.x;
    int n = gcur[b];
    if (n > CAP) n = CAP;
    int base = bstart[b];
    const unsigned* bk = buckets + (size_t)b * CAP;

    hist[t] = 0;
    __syncthreads();
    for (int i = t; i < n; i += 256) atomicAdd(&hist[bk[i] >> 24], 1);
    __syncthreads();

    int v = hist[t];
    scn[t] = v;
    __syncthreads();
    for (int off = 1; off < 256; off <<= 1) {
        int add = (t >= off) ? scn[t - off] : 0;
        __syncthreads();
        scn[t] += add;
        __syncthreads();
    }
    int excl = scn[t] - v;
    int node = b * NPB + t;
    if (node < NN) row_ptr[node] = base + excl;

    hist[t] = excl;  // reuse as cursor
    __syncthreads();
    for (int i = t; i < n; i += 256) {
        unsigned pr = bk[i];
        int pos = atomicAdd(&hist[pr >> 24], 1);
        adj[base + pos] = (int)(pr & 0xFFFFFFu);
    }
}

// ---------------- prep: x -> row-major bf16 AND all weights -> MFMA frag layout ----------------
// frag[(kt*(H/16)+nt)*64 + lane], elem i = W[kt*32 + (lane>>4)*8 + i][nt*16 + (lane&15)]

__device__ __forceinline__ void wfrag_one(const float* __restrict__ W, int H, int idx,
                                          uint4* __restrict__ out) {
    int lane = idx & 63;
    int tile = idx >> 6;
    int ntiles = H >> 4;
    int nt = tile % ntiles;
    int kt = tile / ntiles;
    int kbase = kt * 32 + (lane >> 4) * 8;
    int col = nt * 16 + (lane & 15);
    uint4 r;
    r.x = packbf(W[(size_t)(kbase + 0) * H + col], W[(size_t)(kbase + 1) * H + col]);
    r.y = packbf(W[(size_t)(kbase + 2) * H + col], W[(size_t)(kbase + 3) * H + col]);
    r.z = packbf(W[(size_t)(kbase + 4) * H + col], W[(size_t)(kbase + 5) * H + col]);
    r.w = packbf(W[(size_t)(kbase + 6) * H + col], W[(size_t)(kbase + 7) * H + col]);
    out[idx] = r;
}

__global__ __launch_bounds__(256) void prep_kernel(
    const float* __restrict__ x, unsigned int* __restrict__ x_bf,
    const float* __restrict__ W1l, const float* __restrict__ W1r,
    const float* __restrict__ W2l, const float* __restrict__ W2r,
    const float* __restrict__ W3l, const float* __restrict__ W3r,
    uint4* __restrict__ wf1, uint4* __restrict__ wf2,
    uint4* __restrict__ wf3l, uint4* __restrict__ wf3r) {
    int idx = blockIdx.x * blockDim.x + threadIdx.x;
    if (idx < CVT_N) {
        const float4* p = (const float4*)x + (size_t)idx * 2;
        float4 a = p[0], b = p[1];
        uint4 r;
        r.x = packbf(a.x, a.y);
        r.y = packbf(a.z, a.w);
        r.z = packbf(b.x, b.y);
        r.w = packbf(b.z, b.w);
        ((uint4*)x_bf)[idx] = r;
    } else {
        int k = idx - CVT_N;
        if (k < 2048)       wfrag_one(W1l, 128, k, wf1);
        else if (k < 4096)  wfrag_one(W1r, 128, k - 2048, wf1 + 2048);
        else if (k < 6144)  wfrag_one(W2l, 128, k - 4096, wf2);
        else if (k < 8192)  wfrag_one(W2r, 128, k - 6144, wf2 + 2048);
        else if (k < 9216)  wfrag_one(W3l, 64, k - 8192, wf3l);
        else if (k < 10240) wfrag_one(W3r, 64, k - 9216, wf3r);
    }
}

// ---------------- pull_mean 128-wide, row-major ----------------
// 1 node/wave, 4 waves/block. Lanes: g = l>>4 (edge subgroup), i = l&15 (16B chunk).
// Unmasked full 16-edge iterations; single masked tail (covers end-p in [1,15]).

__global__ __launch_bounds__(256) void pull128_kernel(
    const uint4* __restrict__ xb4, const int* __restrict__ row_ptr,
    const int* __restrict__ adj, uint4* __restrict__ aggb4) {
    int node = blockIdx.x * 4 + (threadIdx.x >> 6);
    int l = threadIdx.x & 63;
    int g = l >> 4;
    int i = l & 15;
    int beg = row_ptr[node], end = row_ptr[node + 1];
    float acc[8];
#pragma unroll
    for (int j = 0; j < 8; ++j) acc[j] = 0.f;

    int p = beg;
    for (; p + 16 <= end; p += 16) {
#pragma unroll
        for (int j = 0; j < 4; ++j) {
            int s = adj[p + j * 4 + g];
            uint4 u = xb4[(size_t)s * 16 + i];
            acc[0] += bflo(u.x);
            acc[1] += bfhi(u.x);
            acc[2] += bflo(u.y);
            acc[3] += bfhi(u.y);
            acc[4] += bflo(u.z);
            acc[5] += bfhi(u.z);
            acc[6] += bflo(u.w);
            acc[7] += bfhi(u.w);
        }
    }
    if (p < end) {
#pragma unroll
        for (int j = 0; j < 4; ++j) {
            int e = p + j * 4 + g;
            bool vv = e < end;
            int s = vv ? adj[e] : 0;
            uint4 u = xb4[(size_t)s * 16 + i];
            float m = vv ? 1.f : 0.f;
            acc[0] = fmaf(m, bflo(u.x), acc[0]);
            acc[1] = fmaf(m, bfhi(u.x), acc[1]);
            acc[2] = fmaf(m, bflo(u.y), acc[2]);
            acc[3] = fmaf(m, bfhi(u.y), acc[3]);
            acc[4] = fmaf(m, bflo(u.z), acc[4]);
            acc[5] = fmaf(m, bfhi(u.z), acc[5]);
            acc[6] = fmaf(m, bflo(u.w), acc[6]);
            acc[7] = fmaf(m, bfhi(u.w), acc[7]);
        }
    }

#pragma unroll
    for (int j = 0; j < 8; ++j) {
        acc[j] += __shfl_xor(acc[j], 16);
        acc[j] += __shfl_xor(acc[j], 32);
    }
    if (g == 0) {
        float inv = 1.0f / (float)(end > beg ? (end - beg) : 1);
        uint4 r;
        r.x = packbf(acc[0] * inv, acc[1] * inv);
        r.y = packbf(acc[2] * inv, acc[3] * inv);
        r.z = packbf(acc[4] * inv, acc[5] * inv);
        r.w = packbf(acc[6] * inv, acc[7] * inv);
        aggb4[(size_t)node * 16 + i] = r;
    }
}

// ---------------- pull_mean 64-wide (z), row-major, fp32 out ----------------

__global__ __launch_bounds__(256) void pull64_kernel(
    const uint2* __restrict__ zb2, const int* __restrict__ row_ptr,
    const int* __restrict__ adj, float* __restrict__ aggout) {
    int node = blockIdx.x * 4 + (threadIdx.x >> 6);
    int l = threadIdx.x & 63;
    int g = l >> 4;
    int i = l & 15;
    int beg = row_ptr[node], end = row_ptr[node + 1];
    float acc[4];
#pragma unroll
    for (int j = 0; j < 4; ++j) acc[j] = 0.f;

    int p = beg;
    for (; p + 16 <= end; p += 16) {
#pragma unroll
        for (int j = 0; j < 4; ++j) {
            int s = adj[p + j * 4 + g];
            uint2 u = zb2[(size_t)s * 16 + i];
            acc[0] += bflo(u.x);
            acc[1] += bfhi(u.x);
            acc[2] += bflo(u.y);
            acc[3] += bfhi(u.y);
        }
    }
    if (p < end) {
#pragma unroll
        for (int j = 0; j < 4; ++j) {
            int e = p + j * 4 + g;
            bool vv = e < end;
            int s = vv ? adj[e] : 0;
            uint2 u = zb2[(size_t)s * 16 + i];
            float m = vv ? 1.f : 0.f;
            acc[0] = fmaf(m, bflo(u.x), acc[0]);
            acc[1] = fmaf(m, bfhi(u.x), acc[1]);
            acc[2] = fmaf(m, bflo(u.y), acc[2]);
            acc[3] = fmaf(m, bfhi(u.y), acc[3]);
        }
    }

#pragma unroll
    for (int j = 0; j < 4; ++j) {
        acc[j] += __shfl_xor(acc[j], 16);
        acc[j] += __shfl_xor(acc[j], 32);
    }
    if (g == 0) {
        float inv = 1.0f / (float)(end > beg ? (end - beg) : 1);
        float4 r;
        r.x = acc[0] * inv;
        r.y = acc[1] * inv;
        r.z = acc[2] * inv;
        r.w = acc[3] * inv;
        *(float4*)(aggout + (size_t)node * 64 + i * 4) = r;
    }
}

// ---------------- MFMA SAGE layer (H=128): out = relu(agg@Wl + xin@Wr + b) ----------------
// FUSE_Z: additionally z = h @ Wz via LDS C->A transpose (bit-identical to a separate
// matmul over the bf16 h). __syncthreads() guarantees LDS write->read ordering.

template <bool FUSE_Z>
__global__ __launch_bounds__(256) void sage_mfma_kernel(
    const uint4* __restrict__ aggA, const uint4* __restrict__ xinA,
    const uint4* __restrict__ wfrag, const float* __restrict__ bias,
    unsigned short* __restrict__ outb,
    const uint4* __restrict__ wfz, unsigned short* __restrict__ zout) {
    extern __shared__ unsigned short hts[];  // FUSE_Z: 4 waves x [16][136]

    const int w = threadIdx.x >> 6;
    const int l = threadIdx.x & 63;
    const int r0 = blockIdx.x * 64 + w * 16;
    int arow = r0 + (l & 15);
    if (arow > NN - 1) arow = NN - 1;
    const int koff = l >> 4;

    f32x4 acc[8];
#pragma unroll
    for (int nt = 0; nt < 8; ++nt) {
        f32x4 z = {0.f, 0.f, 0.f, 0.f};
        acc[nt] = z;
    }

#pragma unroll
    for (int kt = 0; kt < 8; ++kt) {
        const uint4* Ab = (kt < 4) ? aggA : xinA;
        const int ktl = kt & 3;
        bf16x8 av = as_bf8(Ab[(size_t)arow * 16 + ktl * 4 + koff]);
#pragma unroll
        for (int nt = 0; nt < 8; ++nt) {
            bf16x8 bv = as_bf8(wfrag[(kt * 8 + nt) * 64 + l]);
            acc[nt] = __builtin_amdgcn_mfma_f32_16x16x32_bf16(av, bv, acc[nt], 0, 0, 0);
        }
    }

    const int crow0 = r0 + ((l >> 4) << 2);
    const int ccol = l & 15;
#pragma unroll
    for (int nt = 0; nt < 8; ++nt) {
        float bb = bias[nt * 16 + ccol];
#pragma unroll
        for (int q = 0; q < 4; ++q) {
            int r = crow0 + q;
            unsigned short hb = f2bf(fmaxf(acc[nt][q] + bb, 0.f));
            if (r < NN) outb[(size_t)r * 128 + nt * 16 + ccol] = hb;
            if (FUSE_Z) {
                // C layout: row=(l>>4)*4+q (local), col=nt*16+ccol; stride 136 shorts
                hts[((size_t)w * 16 + ((l >> 4) << 2) + q) * 136 + nt * 16 + ccol] = hb;
            }
        }
    }

    if (FUSE_Z) {
        __syncthreads();  // ensure the full 16x128 tile is visible before A-frag reads
        f32x4 accz[4];
#pragma unroll
        for (int nt = 0; nt < 4; ++nt) {
            f32x4 z = {0.f, 0.f, 0.f, 0.f};
            accz[nt] = z;
        }
#pragma unroll
        for (int kt = 0; kt < 4; ++kt) {
            // A-frag: row = l&15, k = kt*32 + (l>>4)*8 + i  (16B-aligned uint4 read)
            const uint4 hv =
                *(const uint4*)&hts[((size_t)w * 16 + (l & 15)) * 136 + kt * 32 + (l >> 4) * 8];
            bf16x8 av = as_bf8(hv);
#pragma unroll
            for (int nt = 0; nt < 4; ++nt) {
                bf16x8 bv = as_bf8(wfz[(kt * 4 + nt) * 64 + l]);
                accz[nt] = __builtin_amdgcn_mfma_f32_16x16x32_bf16(av, bv, accz[nt], 0, 0, 0);
            }
        }
#pragma unroll
        for (int nt = 0; nt < 4; ++nt) {
#pragma unroll
            for (int q = 0; q < 4; ++q) {
                int r = crow0 + q;
                if (r < NN) zout[(size_t)r * 64 + nt * 16 + ccol] = f2bf(accz[nt][q]);
            }
        }
    }
}

// ---------------- final MFMA matmul: out = h2 @ W3r + agg3 + b3 (fp32) ----------------

__global__ __launch_bounds__(256) void mm64_final_kernel(
    const uint4* __restrict__ A, const uint4* __restrict__ wfrag,
    const float* __restrict__ addin, const float* __restrict__ bias,
    float* __restrict__ out) {
    const int w = threadIdx.x >> 6;
    const int l = threadIdx.x & 63;
    const int r0 = blockIdx.x * 64 + w * 16;
    int arow = r0 + (l & 15);
    if (arow > NN - 1) arow = NN - 1;
    const int koff = l >> 4;

    f32x4 acc[4];
#pragma unroll
    for (int nt = 0; nt < 4; ++nt) {
        f32x4 z = {0.f, 0.f, 0.f, 0.f};
        acc[nt] = z;
    }

#pragma unroll
    for (int kt = 0; kt < 4; ++kt) {
        bf16x8 av = as_bf8(A[(size_t)arow * 16 + kt * 4 + koff]);
#pragma unroll
        for (int nt = 0; nt < 4; ++nt) {
            bf16x8 bv = as_bf8(wfrag[(kt * 4 + nt) * 64 + l]);
            acc[nt] = __builtin_amdgcn_mfma_f32_16x16x32_bf16(av, bv, acc[nt], 0, 0, 0);
        }
    }

    const int crow0 = r0 + ((l >> 4) << 2);
    const int ccol = l & 15;
#pragma unroll
    for (int nt = 0; nt < 4; ++nt) {
        int col = nt * 16 + ccol;
#pragma unroll
        for (int q = 0; q < 4; ++q) {
            int r = crow0 + q;
            if (r < NN) {
                out[(size_t)r * 64 + col] =
                    acc[nt][q] + addin[(size_t)r * 64 + col] + bias[col];
            }
        }
    }
}

// ---------------- launcher ----------------

extern "C" void kernel_launch(void* const* d_in, const int* in_sizes, int n_in,
                              void* d_out, int out_size, void* d_ws, size_t ws_size,
                              hipStream_t stream) {
    (void)in_sizes; (void)n_in; (void)out_size; (void)ws_size;

    const float* x   = (const float*)d_in[0];
    const int* eidx  = (const int*)d_in[1];
    const int* src   = eidx;
    const int* dst   = eidx + NE;
    const float* W1l = (const float*)d_in[2];
    const float* W1r = (const float*)d_in[3];
    const float* b1  = (const float*)d_in[4];
    const float* W2l = (const float*)d_in[5];
    const float* W2r = (const float*)d_in[6];
    const float* b2  = (const float*)d_in[7];
    const float* W3l = (const float*)d_in[8];
    const float* W3r = (const float*)d_in[9];
    const float* b3  = (const float*)d_in[10];
    float* out = (float*)d_out;

    size_t off = 0;
    auto carve = [&](size_t bytes) -> void* {
        void* p = (char*)d_ws + off;
        off += (bytes + 255) & ~(size_t)255;
        return p;
    };
    int* gcur    = (int*)carve((size_t)NB * 4);
    int* bstart  = (int*)carve((size_t)(NB + 1) * 4);
    int* row_ptr = (int*)carve((size_t)(NN + 1) * 4);
    int* adj     = (int*)carve((size_t)NE * 4);
    unsigned* buckets = (unsigned*)carve((size_t)NB * CAP * 4);         // 7.6 MB
    unsigned int* x_bf  = (unsigned int*)carve((size_t)NN * 64 * 4);    // [NN][128] bf16
    unsigned int* agg   = (unsigned int*)carve((size_t)NN * 64 * 4);    // [NN][128] bf16
    unsigned int* h1_bf = (unsigned int*)carve((size_t)NN * 64 * 4);
    unsigned int* h2_bf = (unsigned int*)carve((size_t)NN * 64 * 4);
    unsigned int* z_bf  = (unsigned int*)carve((size_t)NN * 32 * 4);    // [NN][64] bf16
    float* agg3         = (float*)carve((size_t)NN * 64 * 4);           // [NN][64] fp32
    uint4* wf1  = (uint4*)carve((size_t)8 * 8 * 64 * 16);
    uint4* wf2  = (uint4*)carve((size_t)8 * 8 * 64 * 16);
    uint4* wf3l = (uint4*)carve((size_t)4 * 4 * 64 * 16);
    uint4* wf3r = (uint4*)carve((size_t)4 * 4 * 64 * 16);

    const int pgrid = (NN + 3) / 4;                         // 25000
    const int mgrid = (NN + 63) / 64;                       // 1563
    const int cgrid = (CVT_N + 10240) / 256;                // 6290 exact

    // --- CSR build: scatter -> scan -> per-bucket finalize ---
    hipMemsetAsync(gcur, 0, (size_t)NB * 4, stream);
    bucket_scatter_kernel<<<NBLK_A, 256, 0, stream>>>(src, dst, gcur, buckets);
    bucket_scan_kernel<<<1, 512, 0, stream>>>(gcur, bstart, row_ptr);
    csr_finalize_kernel<<<NB, 256, 0, stream>>>(buckets, gcur, bstart, row_ptr, adj);

    // --- prep: x cvt + weight frags ---
    prep_kernel<<<cgrid, 256, 0, stream>>>(x, x_bf, W1l, W1r, W2l, W2r, W3l, W3r,
                                           wf1, wf2, wf3l, wf3r);

    // --- layer 1 ---
    pull128_kernel<<<pgrid, 256, 0, stream>>>((const uint4*)x_bf, row_ptr, adj, (uint4*)agg);
    sage_mfma_kernel<false><<<mgrid, 256, 0, stream>>>(
        (const uint4*)agg, (const uint4*)x_bf, wf1, b1, (unsigned short*)h1_bf,
        nullptr, nullptr);
    // --- layer 2 (+ fused z = h2 @ W3l) ---
    pull128_kernel<<<pgrid, 256, 0, stream>>>((const uint4*)h1_bf, row_ptr, adj, (uint4*)agg);
    sage_mfma_kernel<true><<<mgrid, 256, 4 * 16 * 136 * 2, stream>>>(
        (const uint4*)agg, (const uint4*)h1_bf, wf2, b2, (unsigned short*)h2_bf,
        wf3l, (unsigned short*)z_bf);
    // --- layer 3 ---
    pull64_kernel<<<pgrid, 256, 0, stream>>>((const uint2*)z_bf, row_ptr, adj, agg3);
    mm64_final_kernel<<<mgrid, 256, 0, stream>>>((const uint4*)h2_bf, wf3r, agg3, b3, out);
}